// Round 4
// baseline (1074.546 us; speedup 1.0000x reference)
//
#include <hip/hip_runtime.h>
#include <hip/hip_bf16.h>

// GEMM: out[256,1000] = X[256,150528] * C[1000,150528]^T  (fp32 in/out)
// R6: delivered-bytes reduction. BN=128->256 cuts delivered-to-CU traffic 33%
// (X re-read 4x instead of 8x; C still read once). 512 thr / 8 waves (2Mx4N),
// wave tile 128x64, acc=128 VGPR. 64 KB double-buffered XOR-swizzled bf16 LDS.
// Grid = 256 blocks (exactly 1/CU, zero tail): per-bj K range (4704 iters of
// BK=32) split into 64 balanced slices (32x74 + 32x73). fp32 atomicAdd epilogue.

#define BM 256
#define BN 256
#define BK 32
#define NCLS 1000
#define DIM 150528

typedef short bf16x8 __attribute__((ext_vector_type(8)));
typedef float f32x4 __attribute__((ext_vector_type(4)));

static __device__ __forceinline__ unsigned short f2bf(float f) {
    union { __hip_bfloat16 h; unsigned short u; } cv;
    cv.h = __float2bfloat16(f);
    return cv.u;
}

__global__ __launch_bounds__(512, 2) void classifier_gemm(
    const float* __restrict__ X, const float* __restrict__ W,
    float* __restrict__ out)
{
    // bf16 tiles, XOR-swizzled: row = 32 bf16 = 64 B = 4 chunks of 16 B,
    // chunk c of row r stored at c ^ (r & 3).  As 32 KB + Bs 32 KB = 64 KB.
    __shared__ __align__(16) unsigned short As[2][BM * BK];
    __shared__ __align__(16) unsigned short Bs[2][BN * BK];

    const int t    = threadIdx.x;
    const int lane = t & 63;
    const int wave = t >> 6;      // 0..7
    const int wm   = wave >> 2;   // 0..1  (M half: 128 rows)
    const int wn   = wave & 3;    // 0..3  (N quarter: 64 cols)

    // ---- decode + XCD swizzle: the 4 blocks of K-slice sl (bj=0..3) share
    // lin&7 == sl&7 -> same XCD (round-robin dispatch) -> shared X K-slice
    // (2.4 MB) is L2/L3-co-resident for them.
    const int lin = blockIdx.x;                    // 0..255
    const int bj  = (lin >> 3) & 3;                // 0..3
    const int sl  = ((lin >> 5) << 3) | (lin & 7); // 0..63
    const int col0 = bj * BN;

    // balanced K split: slices 0..31 get 74 iters, 32..63 get 73 (sum 4704)
    const int kstart = (sl < 32) ? 74 * sl : 73 * sl + 32;
    const int kiters = (sl < 32) ? 74 : 73;
    const size_t d0 = (size_t)kstart * BK;

    // staging map: 8 lanes cover one 32-float row segment (16 B each)
    const int frow = t >> 3;        // 0..63
    const int fcol = (t & 7) * 4;   // float offset in row

    const float* aptr = X + (size_t)frow * DIM + d0 + fcol;   // rows frow+64k, k=0..3
    const float* bptr[4];                                     // rows col0+frow+64k
    #pragma unroll
    for (int k = 0; k < 4; ++k) {
        int br = col0 + 64 * k + frow;
        if (br >= NCLS) br = NCLS - 1;   // garbage cols >=1000 never stored
        bptr[k] = W + (size_t)br * DIM + d0 + fcol;
    }

    // ---- swizzled LDS offsets (ushort units) ----
    // write: chunk c=(t&7)>>1 of row r -> stored chunk c^(r&3); r&3 == frow&3.
    const int wsw = ((((t & 7) >> 1) ^ (frow & 3)) << 3) + (t & 1) * 4;
    const int wA  = frow * 32 + wsw;           // + k*2048 per 64-row group
    // read: frag chunk q=(lane>>4) of row base+(lane&15); row&3 == lane&3.
    const int rsw   = ((lane >> 4) ^ (lane & 3)) << 3;
    const int a_off = (wm * 128 + (lane & 15)) * 32 + rsw;   // + mt*512
    const int b_off = (wn * 64  + (lane & 15)) * 32 + rsw;   // + nt*512

    f32x4 acc[8][4];
    #pragma unroll
    for (int i = 0; i < 8; ++i)
        #pragma unroll
        for (int j = 0; j < 4; ++j)
            acc[i][j] = (f32x4){0.f, 0.f, 0.f, 0.f};

    // depth-1 staging registers: A 4 + B 4 = 8 float4
    float4 Sa[4], Sb[4];

    auto load_set = [&](size_t koff) {
        #pragma unroll
        for (int k = 0; k < 4; ++k)
            Sa[k] = *(const float4*)(aptr + (size_t)(64 * k) * DIM + koff);
        #pragma unroll
        for (int k = 0; k < 4; ++k)
            Sb[k] = *(const float4*)(bptr[k] + koff);
    };

    auto stage = [&](int buf) {
        #pragma unroll
        for (int k = 0; k < 4; ++k) {
            ushort4 p;
            p.x = f2bf(Sa[k].x); p.y = f2bf(Sa[k].y);
            p.z = f2bf(Sa[k].z); p.w = f2bf(Sa[k].w);
            *(ushort4*)&As[buf][wA + k * 2048] = p;
        }
        #pragma unroll
        for (int k = 0; k < 4; ++k) {
            ushort4 p;
            p.x = f2bf(Sb[k].x); p.y = f2bf(Sb[k].y);
            p.z = f2bf(Sb[k].z); p.w = f2bf(Sb[k].w);
            *(ushort4*)&Bs[buf][wA + k * 2048] = p;
        }
    };

    auto compute = [&](int buf) {
        bf16x8 afr[8], bfr[4];
        #pragma unroll
        for (int mt = 0; mt < 8; ++mt)
            afr[mt] = *(const bf16x8*)&As[buf][a_off + mt * 512];
        #pragma unroll
        for (int nt = 0; nt < 4; ++nt)
            bfr[nt] = *(const bf16x8*)&Bs[buf][b_off + nt * 512];
        #pragma unroll
        for (int mt = 0; mt < 8; ++mt)
            #pragma unroll
            for (int nt = 0; nt < 4; ++nt)
                acc[mt][nt] = __builtin_amdgcn_mfma_f32_16x16x32_bf16(
                    afr[mt], bfr[nt], acc[mt][nt], 0, 0, 0);
    };

    // raw barrier: drain LDS only — global loads stay in flight across it
    auto barrier = [&]() {
        asm volatile("s_waitcnt lgkmcnt(0)" ::: "memory");
        __builtin_amdgcn_s_barrier();
        __builtin_amdgcn_sched_barrier(0);
    };

    // ---- prologue: tile 0
    load_set(0);
    stage(0);
    barrier();

    size_t koff = BK;
    for (int it = 0; it < kiters; ++it) {
        const int cur = it & 1;
        if (it + 1 < kiters) { load_set(koff); koff += BK; }  // issue early
        compute(cur);                                          // covers latency
        if (it + 1 < kiters) stage(cur ^ 1);                   // vmcnt via reg-deps
        barrier();
    }

    // ---- epilogue: atomic-add partial 256x256 tile
    // C/D layout: col = lane&15, row = (lane>>4)*4 + reg
    const int orow0 = wm * 128 + (lane >> 4) * 4;
    const int ocol0 = col0 + wn * 64 + (lane & 15);
    #pragma unroll
    for (int mt = 0; mt < 8; ++mt) {
        #pragma unroll
        for (int nt = 0; nt < 4; ++nt) {
            const int ocol = ocol0 + nt * 16;
            if (ocol < NCLS) {
                #pragma unroll
                for (int e = 0; e < 4; ++e) {
                    const int orow = orow0 + mt * 16 + e;
                    atomicAdd(out + (size_t)orow * NCLS + ocol, acc[mt][nt][e]);
                }
            }
        }
    }
}

extern "C" void kernel_launch(void* const* d_in, const int* in_sizes, int n_in,
                              void* d_out, int out_size, void* d_ws, size_t ws_size,
                              hipStream_t stream) {
    const float* X = (const float*)d_in[0];   // [256, 150528]
    const float* W = (const float*)d_in[1];   // [1000, 150528]
    float* out = (float*)d_out;               // [256, 1000]

    hipMemsetAsync(out, 0, (size_t)out_size * sizeof(float), stream);

    dim3 grid(256);   // 1 block/CU exactly; decoded via swizzle in-kernel
    dim3 block(512);
    classifier_gemm<<<grid, block, 0, stream>>>(X, W, out);
}